// Round 1
// baseline (807.305 us; speedup 1.0000x reference)
//
#include <hip/hip_runtime.h>
#include <math.h>

#define B_ 16
#define C_ 384
#define N_ 1024
#define K_ 9

// ---------------- sq[b][n] = sum_c x[b][c][n]^2 (fp64 accum) ----------------
__global__ void k_sq(const float* __restrict__ x, float* __restrict__ sq) {
  const int idx = blockIdx.x * blockDim.x + threadIdx.x;  // 0..16383
  const int b = idx >> 10, n = idx & 1023;
  const float* xb = x + (size_t)b * C_ * N_ + n;
  double s = 0.0;
#pragma unroll 4
  for (int c = 0; c < C_; ++c) {
    float v = xb[(size_t)c * N_];
    s = fma((double)v, (double)v, s);
  }
  sq[idx] = (float)s;
}

// ---------------- Gram + per-half top-9 ----------------
// block: ((b*16 + rt)*2 + half); rows n0=rt*64..+64, cols m in [half*512, half*512+512)
// 256 thr: ty=tid>>4 row-group (4 rows), tx=tid&15 col-group (8 cols). TM=64, TN=128, kc=16.
__global__ __launch_bounds__(256, 2) void k_gram(const float* __restrict__ x,
                                                 const float* __restrict__ sq,
                                                 float* __restrict__ cd,
                                                 int* __restrict__ ci) {
  const int bid = blockIdx.x;
  const int half = bid & 1;
  const int rt = (bid >> 1) & 15;
  const int b = bid >> 5;
  const int n0 = rt * 64;
  const float* xb = x + (size_t)b * C_ * N_;
  const float* sqb = sq + b * N_;

  __shared__ float A_l[16][64];
  __shared__ float B_l[16][128];
  __shared__ float D_l[64][129];  // +1 pad: scan reads stride 129 = conflict-free

  const int tid = threadIdx.x;
  const int tx = tid & 15;
  const int ty = tid >> 4;

  float dist[K_];
  int idx9[K_];
#pragma unroll
  for (int k = 0; k < K_; ++k) { dist[k] = 3.402823466e38f; idx9[k] = 0; }

  float sqn[4];
#pragma unroll
  for (int r = 0; r < 4; ++r) sqn[r] = sqb[n0 + 4 * ty + r];

  const int la_c = tid >> 4;        // 0..15
  const int la_i = (tid & 15) * 4;  // 0..60
  const int lb_j = (tid & 15) * 8;  // 0..120

  for (int mt = 0; mt < 4; ++mt) {
    const int m0 = half * 512 + mt * 128;
    float acc[4][8] = {};
    for (int kt = 0; kt < C_; kt += 16) {
      *(float4*)&A_l[la_c][la_i] = *(const float4*)&xb[(size_t)(kt + la_c) * N_ + n0 + la_i];
      *(float4*)&B_l[la_c][lb_j] = *(const float4*)&xb[(size_t)(kt + la_c) * N_ + m0 + lb_j];
      *(float4*)&B_l[la_c][lb_j + 4] =
          *(const float4*)&xb[(size_t)(kt + la_c) * N_ + m0 + lb_j + 4];
      __syncthreads();
      // two-level accumulation: 16-k sub-sum then fold into acc (reduces fp32
      // rounding error ~3x vs straight 384-add chain -> fewer kNN tie flips)
      float sub[4][8] = {};
#pragma unroll
      for (int cc = 0; cc < 16; ++cc) {
        float4 av = *(const float4*)&A_l[cc][4 * ty];
        float4 b0 = *(const float4*)&B_l[cc][8 * tx];
        float4 b1 = *(const float4*)&B_l[cc][8 * tx + 4];
        const float a_[4] = {av.x, av.y, av.z, av.w};
        const float b_[8] = {b0.x, b0.y, b0.z, b0.w, b1.x, b1.y, b1.z, b1.w};
#pragma unroll
        for (int r = 0; r < 4; ++r)
#pragma unroll
          for (int q = 0; q < 8; ++q) sub[r][q] = fmaf(a_[r], b_[q], sub[r][q]);
      }
#pragma unroll
      for (int r = 0; r < 4; ++r)
#pragma unroll
        for (int q = 0; q < 8; ++q) acc[r][q] += sub[r][q];
      __syncthreads();
    }
    // d = (sq_n + sq_m) - 2g, self -> +inf-ish (mirrors reference rounding)
#pragma unroll
    for (int r = 0; r < 4; ++r) {
      const int gn = n0 + 4 * ty + r;
#pragma unroll
      for (int q = 0; q < 8; ++q) {
        const int m = m0 + 8 * tx + q;
        float t = sqn[r] + sqb[m];
        float d = fmaf(-2.0f, acc[r][q], t);
        if (m == gn) d = 3.402823466e38f;
        D_l[4 * ty + r][8 * tx + q] = d;
      }
    }
    __syncthreads();
    if (tid < 64) {
      // serial scan, ascending m => stable (lower index wins ties, like lax.top_k)
#pragma unroll 1
      for (int j = 0; j < 128; ++j) {
        float d = D_l[tid][j];
        if (d < dist[K_ - 1]) {
          float cdv = d;
          int cmv = m0 + j;
#pragma unroll
          for (int k = 0; k < K_; ++k) {
            if (dist[k] > cdv) {
              float td = dist[k];
              int tm = idx9[k];
              dist[k] = cdv;
              idx9[k] = cmv;
              cdv = td;
              cmv = tm;
            }
          }
        }
      }
    }
    __syncthreads();
  }
  if (tid < 64) {
    const int node = b * N_ + n0 + tid;
#pragma unroll
    for (int k = 0; k < K_; ++k) {
      cd[(size_t)node * 18 + half * 9 + k] = dist[k];
      ci[(size_t)node * 18 + half * 9 + k] = idx9[k];
    }
  }
}

// ---------------- merge the two sorted half-lists ----------------
__global__ void k_merge(const float* __restrict__ cd, const int* __restrict__ ci,
                        int* __restrict__ nbr) {
  const int node = blockIdx.x * blockDim.x + threadIdx.x;  // 0..16383
  const float* d0 = cd + (size_t)node * 18;
  const int* i0 = ci + (size_t)node * 18;
  int p0 = 0, p1 = 0;
#pragma unroll
  for (int k = 0; k < K_; ++k) {
    float a = d0[p0];
    float bq = d0[9 + p1];
    int t = (a <= bq) ? 1 : 0;  // tie -> half0 (lower indices)
    nbr[(size_t)node * K_ + k] = t ? i0[p0] : i0[9 + p1];
    p0 += t;
    p1 += 1 - t;
  }
}

// ---------------- xw^T[b][co][n] = sum_ci Wg[co][ci] * x[b][ci][n] ----------------
__global__ __launch_bounds__(256, 2) void k_xw(const float* __restrict__ x,
                                               const float* __restrict__ Wg,
                                               float* __restrict__ xw) {
  const int nt = blockIdx.x & 7;
  const int ct = (blockIdx.x >> 3) % 6;
  const int b = blockIdx.x / 48;
  const int co0 = ct * 64, nn0 = nt * 128;
  __shared__ float A_l[16][64];
  __shared__ float B_l[16][128];
  const int tid = threadIdx.x, tx = tid & 15, ty = tid >> 4;
  const float* xb = x + (size_t)b * C_ * N_;
  float acc[4][8] = {};
  const int wa_i = tid & 63, wa_q = tid >> 6;
  const int lb_c = tid >> 4, lb_j = (tid & 15) * 8;
  for (int kt = 0; kt < C_; kt += 16) {
    float4 wv = *(const float4*)&Wg[(size_t)(co0 + wa_i) * C_ + kt + 4 * wa_q];
    A_l[4 * wa_q + 0][wa_i] = wv.x;
    A_l[4 * wa_q + 1][wa_i] = wv.y;
    A_l[4 * wa_q + 2][wa_i] = wv.z;
    A_l[4 * wa_q + 3][wa_i] = wv.w;
    *(float4*)&B_l[lb_c][lb_j] = *(const float4*)&xb[(size_t)(kt + lb_c) * N_ + nn0 + lb_j];
    *(float4*)&B_l[lb_c][lb_j + 4] =
        *(const float4*)&xb[(size_t)(kt + lb_c) * N_ + nn0 + lb_j + 4];
    __syncthreads();
#pragma unroll
    for (int cc = 0; cc < 16; ++cc) {
      float4 av = *(const float4*)&A_l[cc][4 * ty];
      float4 b0 = *(const float4*)&B_l[cc][8 * tx];
      float4 b1 = *(const float4*)&B_l[cc][8 * tx + 4];
      const float a_[4] = {av.x, av.y, av.z, av.w};
      const float b_[8] = {b0.x, b0.y, b0.z, b0.w, b1.x, b1.y, b1.z, b1.w};
#pragma unroll
      for (int r = 0; r < 4; ++r)
#pragma unroll
        for (int q = 0; q < 8; ++q) acc[r][q] = fmaf(a_[r], b_[q], acc[r][q]);
    }
    __syncthreads();
  }
#pragma unroll
  for (int r = 0; r < 4; ++r) {
    float* dst = xw + (size_t)b * C_ * N_ + (size_t)(co0 + 4 * ty + r) * N_ + nn0 + 8 * tx;
    float4 v0 = make_float4(acc[r][0], acc[r][1], acc[r][2], acc[r][3]);
    float4 v1 = make_float4(acc[r][4], acc[r][5], acc[r][6], acc[r][7]);
    *(float4*)dst = v0;
    *(float4*)(dst + 4) = v1;
  }
}

// ---------------- aggregate (deg==10 uniformly) + BN partial stats ----------------
__global__ __launch_bounds__(256) void k_agg(const float* __restrict__ xw,
                                             const int* __restrict__ nbr,
                                             const float* __restrict__ bg,
                                             float* __restrict__ out,
                                             float* __restrict__ stats) {
  const int c = blockIdx.x % C_;
  const int b = blockIdx.x / C_;
  __shared__ alignas(16) int nb_l[N_ * K_];
  __shared__ alignas(16) float row_l[N_];
  __shared__ float w1[4], w2[4];
  const int tid = threadIdx.x;
  const int4* gp = (const int4*)(nbr + (size_t)b * N_ * K_);
  int4* lp = (int4*)nb_l;
  for (int t = tid; t < N_ * K_ / 4; t += 256) lp[t] = gp[t];
  const float4* rp = (const float4*)(xw + ((size_t)b * C_ + c) * N_);
  float4* rl = (float4*)row_l;
  for (int t = tid; t < N_ / 4; t += 256) rl[t] = rp[t];
  __syncthreads();
  const float bgc = bg[c];
  float* outb = out + ((size_t)b * C_ + c) * N_;
  float s1 = 0.f, s2 = 0.f;
#pragma unroll
  for (int s = 0; s < 4; ++s) {
    const int n = tid + 256 * s;
    float a = row_l[n];
    const int* nn_ = &nb_l[n * K_];
#pragma unroll
    for (int k = 0; k < K_; ++k) a += row_l[nn_[k]];
    // norm = fl(rsqrt(10)^2) = 0.099999994f for every edge (deg==10 everywhere)
    float y = fmaf(a, 0.099999994f, bgc);
    outb[n] = y;
    s1 += y;
    s2 = fmaf(y, y, s2);
  }
#pragma unroll
  for (int off = 32; off > 0; off >>= 1) {
    s1 += __shfl_down(s1, off, 64);
    s2 += __shfl_down(s2, off, 64);
  }
  const int lane = tid & 63, wid = tid >> 6;
  if (lane == 0) { w1[wid] = s1; w2[wid] = s2; }
  __syncthreads();
  if (tid == 0) {
    atomicAdd(&stats[c], w1[0] + w1[1] + w1[2] + w1[3]);
    atomicAdd(&stats[C_ + c], w2[0] + w2[1] + w2[2] + w2[3]);
  }
}

// ---------------- BN (batch stats) + tanh-GELU + residual ----------------
__global__ void k_bn(const float* __restrict__ x, const float* __restrict__ gamma,
                     const float* __restrict__ beta, const float* __restrict__ stats,
                     float* __restrict__ out) {
  const int f = blockIdx.x * blockDim.x + threadIdx.x;  // float4 index
  const int e = f * 4;
  const int c = (e >> 10) % C_;
  const float inv = 1.f / 16384.f;
  const float mu = stats[c] * inv;
  const float var = fmaf(-mu, mu, stats[C_ + c] * inv);
  const float sc = gamma[c] * rsqrtf(var + 1e-5f);
  const float sh = fmaf(-mu, sc, beta[c]);
  float4 y = ((const float4*)out)[f];
  float4 xv = ((const float4*)x)[f];
  auto gl = [](float z) {
    float z3 = z * z * z;
    float t = 0.7978845608028654f * fmaf(0.044715f, z3, z);
    float th = tanhf(t);
    return 0.5f * z * (1.f + th);
  };
  float4 o;
  o.x = gl(fmaf(y.x, sc, sh)) + xv.x;
  o.y = gl(fmaf(y.y, sc, sh)) + xv.y;
  o.z = gl(fmaf(y.z, sc, sh)) + xv.z;
  o.w = gl(fmaf(y.w, sc, sh)) + xv.w;
  ((float4*)out)[f] = o;
}

extern "C" void kernel_launch(void* const* d_in, const int* in_sizes, int n_in,
                              void* d_out, int out_size, void* d_ws, size_t ws_size,
                              hipStream_t stream) {
  const float* x = (const float*)d_in[0];
  const float* Wg = (const float*)d_in[1];
  const float* bg = (const float*)d_in[2];
  const float* gamma = (const float*)d_in[3];
  const float* beta = (const float*)d_in[4];
  float* out = (float*)d_out;

  char* ws = (char*)d_ws;
  float* xw = (float*)ws;                       // 25165824 B
  float* sq = (float*)(ws + 25165824);          //    65536 B
  float* cd = (float*)(ws + 25231360);          //  1179648 B
  int* ci_ = (int*)(ws + 26411008);             //  1179648 B
  int* nbr = (int*)(ws + 27590656);             //   589824 B
  float* stats = (float*)(ws + 28180480);       //     3072 B

  hipMemsetAsync(stats, 0, 2 * C_ * sizeof(float), stream);
  k_sq<<<64, 256, 0, stream>>>(x, sq);
  k_gram<<<512, 256, 0, stream>>>(x, sq, cd, ci_);
  k_merge<<<64, 256, 0, stream>>>(cd, ci_, nbr);
  k_xw<<<768, 256, 0, stream>>>(x, Wg, xw);
  k_agg<<<B_ * C_, 256, 0, stream>>>(xw, nbr, bg, out, stats);
  k_bn<<<6144, 256, 0, stream>>>(x, gamma, beta, stats, out);
}

// Round 2
// 595.258 us; speedup vs baseline: 1.3562x; 1.3562x over previous
//
#include <hip/hip_runtime.h>
#include <math.h>

#define B_ 16
#define C_ 384
#define N_ 1024
#define K_ 9

#define AS_ 68   // A_l row stride (floats), padded: 68*4B = 272 = 16*17 (16B-aligned, bank-skewed)
#define BS_ 132  // B_l row stride (floats), padded: 132*4B = 528 = 16*33

// ---------------- sq[b][n] = sum_c x[b][c][n]^2 (fp64 accum) ----------------
__global__ void k_sq(const float* __restrict__ x, float* __restrict__ sq) {
  const int idx = blockIdx.x * blockDim.x + threadIdx.x;  // 0..16383
  const int b = idx >> 10, n = idx & 1023;
  const float* xb = x + (size_t)b * C_ * N_ + n;
  double s = 0.0;
#pragma unroll 4
  for (int c = 0; c < C_; ++c) {
    float v = xb[(size_t)c * N_];
    s = fma((double)v, (double)v, s);
  }
  sq[idx] = (float)s;
}

// ---------------- Gram 64x128 tile + per-tile top-9 ----------------
// grid 2048: bid = ((b*16 + rt)*8 + mt). rows n0=rt*64, cols m0=mt*128.
// 256 thr: ty=tid>>4 -> rows 4ty..4ty+3; tx=tid&15 -> cols {4tx..+3, 64+4tx..+3}
// (split fragment: B-tile LDS reads land 2-way on banks = free; old 8tx was 4-way).
// D_l[64][129] scan scratch overlays A_l/B_l (dead by epilogue).
__global__ __launch_bounds__(256, 4) void k_gram(const float* __restrict__ x,
                                                 const float* __restrict__ sq,
                                                 float* __restrict__ cd,
                                                 int* __restrict__ ci) {
  const int bid = blockIdx.x;
  const int mt = bid & 7;
  const int rt = (bid >> 3) & 15;
  const int b = bid >> 7;
  const int n0 = rt * 64, m0 = mt * 128;
  const float* xb = x + (size_t)b * C_ * N_;
  const float* sqb = sq + b * N_;

  __shared__ float smem[64 * 129];  // 33024 B; A_l = [0,16*AS_), B_l follows, D_l overlays all
  float* A_l = smem;
  float* B_l = smem + 16 * AS_;

  const int tid = threadIdx.x;
  const int tx = tid & 15;
  const int ty = tid >> 4;

  float sqn[4];
#pragma unroll
  for (int r = 0; r < 4; ++r) sqn[r] = sqb[n0 + 4 * ty + r];

  const int la_c = tid >> 4;        // 0..15
  const int la_i = (tid & 15) * 4;  // 0..60
  const int lb_j = (tid & 15) * 8;  // 0..120

  float acc[4][8] = {};
  for (int kt = 0; kt < C_; kt += 16) {
    *(float4*)&A_l[la_c * AS_ + la_i] = *(const float4*)&xb[(size_t)(kt + la_c) * N_ + n0 + la_i];
    *(float4*)&B_l[la_c * BS_ + lb_j] = *(const float4*)&xb[(size_t)(kt + la_c) * N_ + m0 + lb_j];
    *(float4*)&B_l[la_c * BS_ + lb_j + 4] =
        *(const float4*)&xb[(size_t)(kt + la_c) * N_ + m0 + lb_j + 4];
    __syncthreads();
    // two-level accumulation: 16-k sub-sum then fold (keeps kNN-selection accuracy)
    float sub[4][8] = {};
#pragma unroll
    for (int cc = 0; cc < 16; ++cc) {
      float4 av = *(const float4*)&A_l[cc * AS_ + 4 * ty];
      float4 b0 = *(const float4*)&B_l[cc * BS_ + 4 * tx];
      float4 b1 = *(const float4*)&B_l[cc * BS_ + 64 + 4 * tx];
      const float a_[4] = {av.x, av.y, av.z, av.w};
      const float b_[8] = {b0.x, b0.y, b0.z, b0.w, b1.x, b1.y, b1.z, b1.w};
#pragma unroll
      for (int r = 0; r < 4; ++r)
#pragma unroll
        for (int q = 0; q < 8; ++q) sub[r][q] = fmaf(a_[r], b_[q], sub[r][q]);
    }
#pragma unroll
    for (int r = 0; r < 4; ++r)
#pragma unroll
      for (int q = 0; q < 8; ++q) acc[r][q] += sub[r][q];
    __syncthreads();
  }

  // epilogue: d = (sq_n + sq_m) - 2g into D_l (stride 129: scan is 2-way = free)
  float* D_l = smem;
#pragma unroll
  for (int r = 0; r < 4; ++r) {
    const int gn = n0 + 4 * ty + r;
#pragma unroll
    for (int q = 0; q < 8; ++q) {
      const int cl = (q < 4) ? (4 * tx + q) : (64 + 4 * tx + q - 4);
      const int m = m0 + cl;
      float t = sqn[r] + sqb[m];
      float d = fmaf(-2.0f, acc[r][q], t);
      if (m == gn) d = 3.402823466e38f;
      D_l[(4 * ty + r) * 129 + cl] = d;
    }
  }
  __syncthreads();
  if (tid < 64) {
    float dist[K_];
    int idx9[K_];
#pragma unroll
    for (int k = 0; k < K_; ++k) { dist[k] = 3.402823466e38f; idx9[k] = 0; }
    // ascending j => stable (lower index wins ties, like lax.top_k)
#pragma unroll 4
    for (int j = 0; j < 128; ++j) {
      float d = D_l[tid * 129 + j];
      if (d < dist[K_ - 1]) {
        float cdv = d;
        int cmv = m0 + j;
#pragma unroll
        for (int k = 0; k < K_; ++k) {
          if (dist[k] > cdv) {
            float td = dist[k];
            int tm = idx9[k];
            dist[k] = cdv;
            idx9[k] = cmv;
            cdv = td;
            cmv = tm;
          }
        }
      }
    }
    const int node = b * N_ + n0 + tid;
#pragma unroll
    for (int k = 0; k < K_; ++k) {
      cd[(size_t)(mt * 9 + k) * (B_ * N_) + node] = dist[k];  // [slot][node]: coalesced
      ci[(size_t)(mt * 9 + k) * (B_ * N_) + node] = idx9[k];
    }
  }
}

// ---------------- stable 8-way merge of sorted 9-lists ----------------
__global__ void k_merge(const float* __restrict__ cd, const int* __restrict__ ci,
                        int* __restrict__ nbr) {
  const int node = blockIdx.x * blockDim.x + threadIdx.x;  // 0..16383
  float rd[9];
  int ri[9];
#pragma unroll
  for (int k = 0; k < K_; ++k) {
    rd[k] = cd[(size_t)k * (B_ * N_) + node];
    ri[k] = ci[(size_t)k * (B_ * N_) + node];
  }
#pragma unroll
  for (int l = 1; l < 8; ++l) {
#pragma unroll
    for (int e = 0; e < K_; ++e) {
      float d = cd[(size_t)(l * 9 + e) * (B_ * N_) + node];
      int ix = ci[(size_t)(l * 9 + e) * (B_ * N_) + node];
      bool in_ = (d < rd[8]) || (d == rd[8] && ix < ri[8]);
      if (in_) {
        rd[8] = d;
        ri[8] = ix;
#pragma unroll
        for (int k = 8; k >= 1; --k) {
          bool sw = (rd[k] < rd[k - 1]) || (rd[k] == rd[k - 1] && ri[k] < ri[k - 1]);
          float td = sw ? rd[k] : rd[k - 1];
          int ti = sw ? ri[k] : ri[k - 1];
          rd[k] = sw ? rd[k - 1] : rd[k];
          ri[k] = sw ? ri[k - 1] : ri[k];
          rd[k - 1] = td;
          ri[k - 1] = ti;
        }
      }
    }
  }
#pragma unroll
  for (int k = 0; k < K_; ++k) nbr[(size_t)node * K_ + k] = ri[k];
}

// ---------------- xw^T[b][co][n] = sum_ci Wg[co][ci] * x[b][ci][n] ----------------
__global__ __launch_bounds__(256, 4) void k_xw(const float* __restrict__ x,
                                               const float* __restrict__ Wg,
                                               float* __restrict__ xw) {
  const int nt = blockIdx.x & 7;
  const int ct = (blockIdx.x >> 3) % 6;
  const int b = blockIdx.x / 48;
  const int co0 = ct * 64, nn0 = nt * 128;
  __shared__ float A_l[16 * AS_];
  __shared__ float B_l[16 * BS_];
  const int tid = threadIdx.x, tx = tid & 15, ty = tid >> 4;
  const float* xb = x + (size_t)b * C_ * N_;
  float acc[4][8] = {};
  const int wa_i = tid & 63, wa_q = tid >> 6;
  const int lb_c = tid >> 4, lb_j = (tid & 15) * 8;
  for (int kt = 0; kt < C_; kt += 16) {
    float4 wv = *(const float4*)&Wg[(size_t)(co0 + wa_i) * C_ + kt + 4 * wa_q];
    A_l[(4 * wa_q + 0) * AS_ + wa_i] = wv.x;
    A_l[(4 * wa_q + 1) * AS_ + wa_i] = wv.y;
    A_l[(4 * wa_q + 2) * AS_ + wa_i] = wv.z;
    A_l[(4 * wa_q + 3) * AS_ + wa_i] = wv.w;
    *(float4*)&B_l[lb_c * BS_ + lb_j] = *(const float4*)&xb[(size_t)(kt + lb_c) * N_ + nn0 + lb_j];
    *(float4*)&B_l[lb_c * BS_ + lb_j + 4] =
        *(const float4*)&xb[(size_t)(kt + lb_c) * N_ + nn0 + lb_j + 4];
    __syncthreads();
#pragma unroll
    for (int cc = 0; cc < 16; ++cc) {
      float4 av = *(const float4*)&A_l[cc * AS_ + 4 * ty];
      float4 b0 = *(const float4*)&B_l[cc * BS_ + 4 * tx];
      float4 b1 = *(const float4*)&B_l[cc * BS_ + 64 + 4 * tx];
      const float a_[4] = {av.x, av.y, av.z, av.w};
      const float b_[8] = {b0.x, b0.y, b0.z, b0.w, b1.x, b1.y, b1.z, b1.w};
#pragma unroll
      for (int r = 0; r < 4; ++r)
#pragma unroll
        for (int q = 0; q < 8; ++q) acc[r][q] = fmaf(a_[r], b_[q], acc[r][q]);
    }
    __syncthreads();
  }
#pragma unroll
  for (int r = 0; r < 4; ++r) {
    float* dst = xw + (size_t)b * C_ * N_ + (size_t)(co0 + 4 * ty + r) * N_ + nn0;
    *(float4*)(dst + 4 * tx) = make_float4(acc[r][0], acc[r][1], acc[r][2], acc[r][3]);
    *(float4*)(dst + 64 + 4 * tx) = make_float4(acc[r][4], acc[r][5], acc[r][6], acc[r][7]);
  }
}

// ---------------- aggregate (deg==10 uniformly) + BN partial stats ----------------
__global__ __launch_bounds__(256) void k_agg(const float* __restrict__ xw,
                                             const int* __restrict__ nbr,
                                             const float* __restrict__ bg,
                                             float* __restrict__ out,
                                             float* __restrict__ stats) {
  const int c = blockIdx.x % C_;
  const int b = blockIdx.x / C_;
  __shared__ alignas(16) int nb_l[N_ * K_];
  __shared__ alignas(16) float row_l[N_];
  __shared__ float w1[4], w2[4];
  const int tid = threadIdx.x;
  const int4* gp = (const int4*)(nbr + (size_t)b * N_ * K_);
  int4* lp = (int4*)nb_l;
  for (int t = tid; t < N_ * K_ / 4; t += 256) lp[t] = gp[t];
  const float4* rp = (const float4*)(xw + ((size_t)b * C_ + c) * N_);
  float4* rl = (float4*)row_l;
  for (int t = tid; t < N_ / 4; t += 256) rl[t] = rp[t];
  __syncthreads();
  const float bgc = bg[c];
  float* outb = out + ((size_t)b * C_ + c) * N_;
  float s1 = 0.f, s2 = 0.f;
#pragma unroll
  for (int s = 0; s < 4; ++s) {
    const int n = tid + 256 * s;
    float a = row_l[n];
    const int* nn_ = &nb_l[n * K_];
#pragma unroll
    for (int k = 0; k < K_; ++k) a += row_l[nn_[k]];
    // norm = fl(rsqrt(10)^2) = 0.099999994f for every edge (deg==10 everywhere)
    float y = fmaf(a, 0.099999994f, bgc);
    outb[n] = y;
    s1 += y;
    s2 = fmaf(y, y, s2);
  }
#pragma unroll
  for (int off = 32; off > 0; off >>= 1) {
    s1 += __shfl_down(s1, off, 64);
    s2 += __shfl_down(s2, off, 64);
  }
  const int lane = tid & 63, wid = tid >> 6;
  if (lane == 0) { w1[wid] = s1; w2[wid] = s2; }
  __syncthreads();
  if (tid == 0) {
    atomicAdd(&stats[c], w1[0] + w1[1] + w1[2] + w1[3]);
    atomicAdd(&stats[C_ + c], w2[0] + w2[1] + w2[2] + w2[3]);
  }
}

// ---------------- BN (batch stats) + tanh-GELU + residual ----------------
__global__ void k_bn(const float* __restrict__ x, const float* __restrict__ gamma,
                     const float* __restrict__ beta, const float* __restrict__ stats,
                     float* __restrict__ out) {
  const int f = blockIdx.x * blockDim.x + threadIdx.x;  // float4 index
  const int e = f * 4;
  const int c = (e >> 10) % C_;
  const float inv = 1.f / 16384.f;
  const float mu = stats[c] * inv;
  const float var = fmaf(-mu, mu, stats[C_ + c] * inv);
  const float sc = gamma[c] * rsqrtf(var + 1e-5f);
  const float sh = fmaf(-mu, sc, beta[c]);
  float4 y = ((const float4*)out)[f];
  float4 xv = ((const float4*)x)[f];
  auto gl = [](float z) {
    float z3 = z * z * z;
    float t = 0.7978845608028654f * fmaf(0.044715f, z3, z);
    float th = tanhf(t);
    return 0.5f * z * (1.f + th);
  };
  float4 o;
  o.x = gl(fmaf(y.x, sc, sh)) + xv.x;
  o.y = gl(fmaf(y.y, sc, sh)) + xv.y;
  o.z = gl(fmaf(y.z, sc, sh)) + xv.z;
  o.w = gl(fmaf(y.w, sc, sh)) + xv.w;
  ((float4*)out)[f] = o;
}

extern "C" void kernel_launch(void* const* d_in, const int* in_sizes, int n_in,
                              void* d_out, int out_size, void* d_ws, size_t ws_size,
                              hipStream_t stream) {
  const float* x = (const float*)d_in[0];
  const float* Wg = (const float*)d_in[1];
  const float* bg = (const float*)d_in[2];
  const float* gamma = (const float*)d_in[3];
  const float* beta = (const float*)d_in[4];
  float* out = (float*)d_out;

  // ws layout (cd/ci dead after k_merge -> xw overlays them):
  char* ws = (char*)d_ws;
  float* sq = (float*)ws;                    // @0,          65,536 B
  float* cd = (float*)(ws + 65536);          // @65,536      4,718,592 B
  int* ci_ = (int*)(ws + 4784128);           // @4,784,128   4,718,592 B
  float* xw = (float*)(ws + 65536);          // @65,536      25,165,824 B (overlays cd/ci)
  int* nbr = (int*)(ws + 25231360);          // @25,231,360  589,824 B
  float* stats = (float*)(ws + 25821184);    // @25,821,184  3,072 B

  hipMemsetAsync(stats, 0, 2 * C_ * sizeof(float), stream);
  k_sq<<<64, 256, 0, stream>>>(x, sq);
  k_gram<<<2048, 256, 0, stream>>>(x, sq, cd, ci_);
  k_merge<<<64, 256, 0, stream>>>(cd, ci_, nbr);
  k_xw<<<768, 256, 0, stream>>>(x, Wg, xw);  // after k_merge: xw overlays cd/ci
  k_agg<<<B_ * C_, 256, 0, stream>>>(xw, nbr, bg, out, stats);
  k_bn<<<6144, 256, 0, stream>>>(x, gamma, beta, stats, out);
}

// Round 3
// 444.409 us; speedup vs baseline: 1.8166x; 1.3394x over previous
//
#include <hip/hip_runtime.h>
#include <math.h>

#define B_ 16
#define C_ 384
#define N_ 1024
#define K_ 9

typedef _Float16 f16x8 __attribute__((ext_vector_type(8)));
typedef _Float16 f16x4 __attribute__((ext_vector_type(4)));
typedef float f32x4 __attribute__((ext_vector_type(4)));

// ---------------- transpose + fp16 split: x[b][c][n] -> xhT/xlT [b][n][c] ----------------
__global__ void k_cvt(const float* __restrict__ x, ushort* __restrict__ xhT,
                      ushort* __restrict__ xlT) {
  const int bid = blockIdx.x;          // ((b*16 + nt)*12 + ct)
  const int ct = bid % 12;
  const int nt = (bid / 12) & 15;
  const int b = bid / 192;
  const int c0 = ct * 32, n0 = nt * 64;
  __shared__ float ld[32 * 65];
  const int t = threadIdx.x;
  {
    const int c = t >> 3, n8 = (t & 7) * 8;
    const float* src = x + ((size_t)(b * C_ + c0 + c) * N_ + n0 + n8);
    float4 v0 = *(const float4*)src;
    float4 v1 = *(const float4*)(src + 4);
    float vv[8] = {v0.x, v0.y, v0.z, v0.w, v1.x, v1.y, v1.z, v1.w};
#pragma unroll
    for (int j = 0; j < 8; ++j) ld[c * 65 + n8 + j] = vv[j];
  }
  __syncthreads();
  {
    const int n = t >> 2, c8 = (t & 3) * 8;
    f16x8 hv, lv;
#pragma unroll
    for (int j = 0; j < 8; ++j) {
      float v = ld[(c8 + j) * 65 + n];
      _Float16 h = (_Float16)v;
      _Float16 l = (_Float16)(v - (float)h);
      hv[j] = h;
      lv[j] = l;
    }
    const size_t off = (size_t)(b * N_ + n0 + n) * C_ + c0 + c8;
    *(f16x8*)(xhT + off) = hv;
    *(f16x8*)(xlT + off) = lv;
  }
}

// ---------------- Wg -> WgH/WgL (same [co][ci] layout) ----------------
__global__ void k_cvtw(const float* __restrict__ Wg, ushort* __restrict__ WgH,
                       ushort* __restrict__ WgL) {
  const int i = (blockIdx.x * 256 + threadIdx.x) * 4;  // 144 blocks
  float4 v = *(const float4*)(Wg + i);
  float vv[4] = {v.x, v.y, v.z, v.w};
  f16x4 hv, lv;
#pragma unroll
  for (int j = 0; j < 4; ++j) {
    _Float16 h = (_Float16)vv[j];
    hv[j] = h;
    lv[j] = (_Float16)(vv[j] - (float)h);
  }
  *(f16x4*)(WgH + i) = hv;
  *(f16x4*)(WgL + i) = lv;
}

// ---------------- sq[b][n] = sum_c x[b][c][n]^2 (fp64 accum) ----------------
__global__ void k_sq(const float* __restrict__ x, float* __restrict__ sq) {
  const int idx = blockIdx.x * blockDim.x + threadIdx.x;
  const int b = idx >> 10, n = idx & 1023;
  const float* xb = x + (size_t)b * C_ * N_ + n;
  double s = 0.0;
#pragma unroll 4
  for (int c = 0; c < C_; ++c) {
    float v = xb[(size_t)c * N_];
    s = fma((double)v, (double)v, s);
  }
  sq[idx] = (float)s;
}

// ---------------- MFMA Gram 128x128 tile + per-tile top-9 ----------------
// split-f16 3-term: G = AhBh + AlBh + AhBl (fp32-class accuracy for kNN selection)
__global__ __launch_bounds__(256, 3) void k_gram(const ushort* __restrict__ xhT,
                                                 const ushort* __restrict__ xlT,
                                                 const float* __restrict__ sq,
                                                 float* __restrict__ cd,
                                                 int* __restrict__ ci) {
  const int bid = blockIdx.x;  // ((b*8 + rt)*8 + mt)
  const int mt = bid & 7, rt = (bid >> 3) & 7, b = bid >> 6;
  const int n0 = rt * 128, m0 = mt * 128;
  __shared__ alignas(16) char sm[40960];  // Ah@0 Al@10240 Bh@20480 Bl@30720 (128x[80B]); D overlays
  const int t = threadIdx.x;
  const int lane = t & 63, wid = t >> 6, quad = lane >> 4, lrow = lane & 15;
  const int wr = wid >> 1, wc = wid & 1;

  f32x4 acc[4][4];
#pragma unroll
  for (int mi = 0; mi < 4; ++mi)
#pragma unroll
    for (int ni = 0; ni < 4; ++ni) acc[mi][ni] = (f32x4){0.f, 0.f, 0.f, 0.f};

  const char* srcs[4] = {(const char*)(xhT + (size_t)(b * N_ + n0) * C_),
                         (const char*)(xlT + (size_t)(b * N_ + n0) * C_),
                         (const char*)(xhT + (size_t)(b * N_ + m0) * C_),
                         (const char*)(xlT + (size_t)(b * N_ + m0) * C_)};

  for (int kt = 0; kt < C_; kt += 32) {
    __syncthreads();
#pragma unroll
    for (int i = 0; i < 8; ++i) {
      const int g = i * 256 + t;
      const int arr = g >> 9, row = (g >> 2) & 127, ch = g & 3;
      *(uint4*)(sm + arr * 10240 + row * 80 + ch * 16) =
          *(const uint4*)(srcs[arr] + (size_t)row * 768 + kt * 2 + ch * 16);
    }
    __syncthreads();
    f16x8 ah[4], al[4];
#pragma unroll
    for (int mi = 0; mi < 4; ++mi) {
      const int ro = (wr * 64 + mi * 16 + lrow) * 80 + quad * 16;
      ah[mi] = *(const f16x8*)(sm + ro);
      al[mi] = *(const f16x8*)(sm + 10240 + ro);
    }
#pragma unroll
    for (int ni = 0; ni < 4; ++ni) {
      const int ro = (wc * 64 + ni * 16 + lrow) * 80 + quad * 16;
      f16x8 bh = *(const f16x8*)(sm + 20480 + ro);
      f16x8 bl = *(const f16x8*)(sm + 30720 + ro);
#pragma unroll
      for (int mi = 0; mi < 4; ++mi) {
        acc[mi][ni] = __builtin_amdgcn_mfma_f32_16x16x32_f16(ah[mi], bh, acc[mi][ni], 0, 0, 0);
        acc[mi][ni] = __builtin_amdgcn_mfma_f32_16x16x32_f16(al[mi], bh, acc[mi][ni], 0, 0, 0);
        acc[mi][ni] = __builtin_amdgcn_mfma_f32_16x16x32_f16(ah[mi], bl, acc[mi][ni], 0, 0, 0);
      }
    }
  }

  // epilogue: d = (sq_n + sq_m) - 2g ; two 64-row halves through D overlay, top-9 scan
  const float* sqb = sq + b * N_;
  float sqm[4];
#pragma unroll
  for (int ni = 0; ni < 4; ++ni) sqm[ni] = sqb[m0 + wc * 64 + ni * 16 + lrow];
  float sqn_[4][4];
#pragma unroll
  for (int mi = 0; mi < 4; ++mi)
#pragma unroll
    for (int r = 0; r < 4; ++r) sqn_[mi][r] = sqb[n0 + wr * 64 + mi * 16 + quad * 4 + r];

  float* D = (float*)sm;
  for (int ph = 0; ph < 2; ++ph) {
    __syncthreads();
    if (wr == ph) {
#pragma unroll
      for (int mi = 0; mi < 4; ++mi)
#pragma unroll
        for (int ni = 0; ni < 4; ++ni)
#pragma unroll
          for (int r = 0; r < 4; ++r) {
            const int rl = mi * 16 + quad * 4 + r;   // 0..63
            const int cl = wc * 64 + ni * 16 + lrow; // 0..127
            const int ng = n0 + ph * 64 + rl, mg = m0 + cl;
            float d = fmaf(-2.f, acc[mi][ni][r], sqn_[mi][r] + sqm[ni]);
            if (mg == ng) d = 3.402823466e38f;
            D[rl * 129 + cl] = d;
          }
    }
    __syncthreads();
    if (t < 64) {
      float dist[K_];
      int idx9[K_];
#pragma unroll
      for (int k = 0; k < K_; ++k) { dist[k] = 3.402823466e38f; idx9[k] = 0; }
#pragma unroll 4
      for (int j = 0; j < 128; ++j) {  // ascending j => stable ties (lower index wins)
        float d = D[t * 129 + j];
        if (d < dist[K_ - 1]) {
          float cdv = d;
          int cmv = m0 + j;
#pragma unroll
          for (int k = 0; k < K_; ++k) {
            if (dist[k] > cdv) {
              float td = dist[k];
              int tm = idx9[k];
              dist[k] = cdv;
              idx9[k] = cmv;
              cdv = td;
              cmv = tm;
            }
          }
        }
      }
      const int node = b * N_ + n0 + ph * 64 + t;
#pragma unroll
      for (int k = 0; k < K_; ++k) {
        cd[(size_t)(mt * 9 + k) * (B_ * N_) + node] = dist[k];
        ci[(size_t)(mt * 9 + k) * (B_ * N_) + node] = idx9[k];
      }
    }
  }
}

// ---------------- stable 8-way merge of sorted 9-lists ----------------
__global__ void k_merge(const float* __restrict__ cd, const int* __restrict__ ci,
                        int* __restrict__ nbr) {
  const int node = blockIdx.x * blockDim.x + threadIdx.x;
  float rd[9];
  int ri[9];
#pragma unroll
  for (int k = 0; k < K_; ++k) {
    rd[k] = cd[(size_t)k * (B_ * N_) + node];
    ri[k] = ci[(size_t)k * (B_ * N_) + node];
  }
#pragma unroll
  for (int l = 1; l < 8; ++l) {
#pragma unroll
    for (int e = 0; e < K_; ++e) {
      float d = cd[(size_t)(l * 9 + e) * (B_ * N_) + node];
      int ix = ci[(size_t)(l * 9 + e) * (B_ * N_) + node];
      bool in_ = (d < rd[8]) || (d == rd[8] && ix < ri[8]);
      if (in_) {
        rd[8] = d;
        ri[8] = ix;
#pragma unroll
        for (int k = 8; k >= 1; --k) {
          bool sw = (rd[k] < rd[k - 1]) || (rd[k] == rd[k - 1] && ri[k] < ri[k - 1]);
          float td = sw ? rd[k] : rd[k - 1];
          int ti = sw ? ri[k] : ri[k - 1];
          rd[k] = sw ? rd[k - 1] : rd[k];
          ri[k] = sw ? ri[k - 1] : ri[k];
          rd[k - 1] = td;
          ri[k - 1] = ti;
        }
      }
    }
  }
#pragma unroll
  for (int k = 0; k < K_; ++k) nbr[(size_t)node * K_ + k] = ri[k];
}

// ---------------- MFMA xw[b][co][n]: A=Wg(h/l) [co][ci], B=xT(h/l) [n][ci] ----------------
__global__ __launch_bounds__(256, 4) void k_xw(const ushort* __restrict__ xhT,
                                               const ushort* __restrict__ xlT,
                                               const ushort* __restrict__ WgH,
                                               const ushort* __restrict__ WgL,
                                               float* __restrict__ xw) {
  const int bid = blockIdx.x;  // ((b*8 + nt)*6 + ct)
  const int ct = bid % 6;
  const int nt = (bid / 6) & 7;
  const int b = bid / 48;
  const int co0 = ct * 64, n0 = nt * 128;
  __shared__ alignas(16) char sm[30720];  // WgH@0 WgL@5120 (64x80B); xhT@10240 xlT@20480 (128x80B)
  const int t = threadIdx.x;
  const int lane = t & 63, wid = t >> 6, quad = lane >> 4, lrow = lane & 15;
  const int wr = wid >> 1, wc = wid & 1;  // wr: n-half(64), wc: co-half(32)

  f32x4 acc[2][4];
#pragma unroll
  for (int mi = 0; mi < 2; ++mi)
#pragma unroll
    for (int ni = 0; ni < 4; ++ni) acc[mi][ni] = (f32x4){0.f, 0.f, 0.f, 0.f};

  const char* asrc[2] = {(const char*)(WgH + (size_t)co0 * C_),
                         (const char*)(WgL + (size_t)co0 * C_)};
  const char* bsrc[2] = {(const char*)(xhT + (size_t)(b * N_ + n0) * C_),
                         (const char*)(xlT + (size_t)(b * N_ + n0) * C_)};

  for (int kt = 0; kt < C_; kt += 32) {
    __syncthreads();
#pragma unroll
    for (int i = 0; i < 2; ++i) {  // A: 512 chunks
      const int g = i * 256 + t;
      const int arr = g >> 8, row = (g >> 2) & 63, ch = g & 3;
      *(uint4*)(sm + arr * 5120 + row * 80 + ch * 16) =
          *(const uint4*)(asrc[arr] + (size_t)row * 768 + kt * 2 + ch * 16);
    }
#pragma unroll
    for (int i = 0; i < 4; ++i) {  // B: 1024 chunks
      const int g = i * 256 + t;
      const int arr = g >> 9, row = (g >> 2) & 127, ch = g & 3;
      *(uint4*)(sm + 10240 + arr * 10240 + row * 80 + ch * 16) =
          *(const uint4*)(bsrc[arr] + (size_t)row * 768 + kt * 2 + ch * 16);
    }
    __syncthreads();
    f16x8 bh[4], bl[4];
#pragma unroll
    for (int ni = 0; ni < 4; ++ni) {
      const int ro = (wr * 64 + ni * 16 + lrow) * 80 + quad * 16;
      bh[ni] = *(const f16x8*)(sm + 10240 + ro);
      bl[ni] = *(const f16x8*)(sm + 20480 + ro);
    }
#pragma unroll
    for (int mi = 0; mi < 2; ++mi) {
      const int ro = (wc * 32 + mi * 16 + lrow) * 80 + quad * 16;
      f16x8 ah = *(const f16x8*)(sm + ro);
      f16x8 al = *(const f16x8*)(sm + 5120 + ro);
#pragma unroll
      for (int ni = 0; ni < 4; ++ni) {
        acc[mi][ni] = __builtin_amdgcn_mfma_f32_16x16x32_f16(ah, bh[ni], acc[mi][ni], 0, 0, 0);
        acc[mi][ni] = __builtin_amdgcn_mfma_f32_16x16x32_f16(al, bh[ni], acc[mi][ni], 0, 0, 0);
        acc[mi][ni] = __builtin_amdgcn_mfma_f32_16x16x32_f16(ah, bl[ni], acc[mi][ni], 0, 0, 0);
      }
    }
  }
#pragma unroll
  for (int mi = 0; mi < 2; ++mi)
#pragma unroll
    for (int ni = 0; ni < 4; ++ni)
#pragma unroll
      for (int r = 0; r < 4; ++r) {
        const int c_g = co0 + wc * 32 + mi * 16 + quad * 4 + r;
        const int n_g = n0 + wr * 64 + ni * 16 + lrow;
        xw[((size_t)b * C_ + c_g) * N_ + n_g] = acc[mi][ni][r];
      }
}

// ---------------- aggregate (deg==10 uniformly) + BN partial stats ----------------
__global__ __launch_bounds__(256) void k_agg(const float* __restrict__ xw,
                                             const int* __restrict__ nbr,
                                             const float* __restrict__ bg,
                                             float* __restrict__ out,
                                             float* __restrict__ stats) {
  const int c = blockIdx.x % C_;
  const int b = blockIdx.x / C_;
  __shared__ alignas(16) int nb_l[N_ * K_];
  __shared__ alignas(16) float row_l[N_];
  __shared__ float w1[4], w2[4];
  const int tid = threadIdx.x;
  const int4* gp = (const int4*)(nbr + (size_t)b * N_ * K_);
  int4* lp = (int4*)nb_l;
  for (int t = tid; t < N_ * K_ / 4; t += 256) lp[t] = gp[t];
  const float4* rp = (const float4*)(xw + ((size_t)b * C_ + c) * N_);
  float4* rl = (float4*)row_l;
  for (int t = tid; t < N_ / 4; t += 256) rl[t] = rp[t];
  __syncthreads();
  const float bgc = bg[c];
  float* outb = out + ((size_t)b * C_ + c) * N_;
  float s1 = 0.f, s2 = 0.f;
#pragma unroll
  for (int s = 0; s < 4; ++s) {
    const int n = tid + 256 * s;
    float a = row_l[n];
    const int* nn_ = &nb_l[n * K_];
#pragma unroll
    for (int k = 0; k < K_; ++k) a += row_l[nn_[k]];
    float y = fmaf(a, 0.099999994f, bgc);
    outb[n] = y;
    s1 += y;
    s2 = fmaf(y, y, s2);
  }
#pragma unroll
  for (int off = 32; off > 0; off >>= 1) {
    s1 += __shfl_down(s1, off, 64);
    s2 += __shfl_down(s2, off, 64);
  }
  const int lane = tid & 63, wid = tid >> 6;
  if (lane == 0) { w1[wid] = s1; w2[wid] = s2; }
  __syncthreads();
  if (tid == 0) {
    atomicAdd(&stats[c], w1[0] + w1[1] + w1[2] + w1[3]);
    atomicAdd(&stats[C_ + c], w2[0] + w2[1] + w2[2] + w2[3]);
  }
}

// ---------------- BN (batch stats) + tanh-GELU + residual ----------------
__global__ void k_bn(const float* __restrict__ x, const float* __restrict__ gamma,
                     const float* __restrict__ beta, const float* __restrict__ stats,
                     float* __restrict__ out) {
  const int f = blockIdx.x * blockDim.x + threadIdx.x;
  const int e = f * 4;
  const int c = (e >> 10) % C_;
  const float inv = 1.f / 16384.f;
  const float mu = stats[c] * inv;
  const float var = fmaf(-mu, mu, stats[C_ + c] * inv);
  const float sc = gamma[c] * rsqrtf(var + 1e-5f);
  const float sh = fmaf(-mu, sc, beta[c]);
  float4 y = ((const float4*)out)[f];
  float4 xv = ((const float4*)x)[f];
  auto gl = [](float z) {
    float z3 = z * z * z;
    float t = 0.7978845608028654f * fmaf(0.044715f, z3, z);
    float th = tanhf(t);
    return 0.5f * z * (1.f + th);
  };
  float4 o;
  o.x = gl(fmaf(y.x, sc, sh)) + xv.x;
  o.y = gl(fmaf(y.y, sc, sh)) + xv.y;
  o.z = gl(fmaf(y.z, sc, sh)) + xv.z;
  o.w = gl(fmaf(y.w, sc, sh)) + xv.w;
  ((float4*)out)[f] = o;
}

extern "C" void kernel_launch(void* const* d_in, const int* in_sizes, int n_in,
                              void* d_out, int out_size, void* d_ws, size_t ws_size,
                              hipStream_t stream) {
  const float* x = (const float*)d_in[0];
  const float* Wg = (const float*)d_in[1];
  const float* bg = (const float*)d_in[2];
  const float* gamma = (const float*)d_in[3];
  const float* beta = (const float*)d_in[4];
  float* out = (float*)d_out;

  char* ws = (char*)d_ws;
  ushort* xhT = (ushort*)ws;                    // @0          12,582,912
  ushort* xlT = (ushort*)(ws + 12582912);       // @12,582,912 12,582,912
  ushort* WgH = (ushort*)(ws + 25165824);       // @25,165,824    294,912
  ushort* WgL = (ushort*)(ws + 25460736);       // @25,460,736    294,912
  float* sq = (float*)(ws + 25755648);          // @25,755,648     65,536
  float* cd = (float*)(ws + 25821184);          // @25,821,184  4,718,592
  int* ci_ = (int*)(ws + 30539776);             // @30,539,776  4,718,592
  float* xw = (float*)(ws + 25821184);          // overlays cd/ci (dead after k_merge): 25,165,824
  int* nbr = (int*)(ws + 50987008);             // @50,987,008    589,824
  float* stats = (float*)(ws + 51576832);       // @51,576,832      3,072

  hipMemsetAsync(stats, 0, 2 * C_ * sizeof(float), stream);
  k_cvt<<<3072, 256, 0, stream>>>(x, xhT, xlT);
  k_cvtw<<<144, 256, 0, stream>>>(Wg, WgH, WgL);
  k_sq<<<64, 256, 0, stream>>>(x, sq);
  k_gram<<<1024, 256, 0, stream>>>(xhT, xlT, sq, cd, ci_);
  k_merge<<<64, 256, 0, stream>>>(cd, ci_, nbr);
  k_xw<<<768, 256, 0, stream>>>(xhT, xlT, WgH, WgL, xw);
  k_agg<<<B_ * C_, 256, 0, stream>>>(xw, nbr, bg, out, stats);
  k_bn<<<6144, 256, 0, stream>>>(x, gamma, beta, stats, out);
}

// Round 4
// 406.866 us; speedup vs baseline: 1.9842x; 1.0923x over previous
//
#include <hip/hip_runtime.h>
#include <math.h>

#define B_ 16
#define C_ 384
#define N_ 1024
#define K_ 9

typedef _Float16 f16x8 __attribute__((ext_vector_type(8)));
typedef _Float16 f16x4 __attribute__((ext_vector_type(4)));
typedef float f32x4 __attribute__((ext_vector_type(4)));

__device__ __forceinline__ void gld_lds16(const void* g, void* l) {
  __builtin_amdgcn_global_load_lds((const __attribute__((address_space(1))) void*)g,
                                   (__attribute__((address_space(3))) void*)l, 16, 0, 0);
}

// ---------------- transpose + fp16 split: x[b][c][n] -> xhT/xlT [b][n][c] ----------------
__global__ void k_cvt(const float* __restrict__ x, ushort* __restrict__ xhT,
                      ushort* __restrict__ xlT) {
  const int bid = blockIdx.x;  // ((b*16 + nt)*12 + ct)
  const int ct = bid % 12;
  const int nt = (bid / 12) & 15;
  const int b = bid / 192;
  const int c0 = ct * 32, n0 = nt * 64;
  __shared__ float ld[32 * 65];
  const int t = threadIdx.x;
  {
    const int c = t >> 3, n8 = (t & 7) * 8;
    const float* src = x + ((size_t)(b * C_ + c0 + c) * N_ + n0 + n8);
    float4 v0 = *(const float4*)src;
    float4 v1 = *(const float4*)(src + 4);
    float vv[8] = {v0.x, v0.y, v0.z, v0.w, v1.x, v1.y, v1.z, v1.w};
#pragma unroll
    for (int j = 0; j < 8; ++j) ld[c * 65 + n8 + j] = vv[j];
  }
  __syncthreads();
  {
    const int n = t >> 2, c8 = (t & 3) * 8;
    f16x8 hv, lv;
#pragma unroll
    for (int j = 0; j < 8; ++j) {
      float v = ld[(c8 + j) * 65 + n];
      _Float16 h = (_Float16)v;
      _Float16 l = (_Float16)(v - (float)h);
      hv[j] = h;
      lv[j] = l;
    }
    const size_t off = (size_t)(b * N_ + n0 + n) * C_ + c0 + c8;
    *(f16x8*)(xhT + off) = hv;
    *(f16x8*)(xlT + off) = lv;
  }
}

// ---------------- Wg -> WgH/WgL (same [co][ci] layout) ----------------
__global__ void k_cvtw(const float* __restrict__ Wg, ushort* __restrict__ WgH,
                       ushort* __restrict__ WgL) {
  const int i = (blockIdx.x * 256 + threadIdx.x) * 4;  // 144 blocks
  float4 v = *(const float4*)(Wg + i);
  float vv[4] = {v.x, v.y, v.z, v.w};
  f16x4 hv, lv;
#pragma unroll
  for (int j = 0; j < 4; ++j) {
    _Float16 h = (_Float16)vv[j];
    hv[j] = h;
    lv[j] = (_Float16)(vv[j] - (float)h);
  }
  *(f16x4*)(WgH + i) = hv;
  *(f16x4*)(WgL + i) = lv;
}

// ---------------- sq[b][n] = sum_c x[b][c][n]^2 (fp64 accum) ----------------
__global__ void k_sq(const float* __restrict__ x, float* __restrict__ sq) {
  const int idx = blockIdx.x * blockDim.x + threadIdx.x;
  const int b = idx >> 10, n = idx & 1023;
  const float* xb = x + (size_t)b * C_ * N_ + n;
  double s = 0.0;
#pragma unroll 4
  for (int c = 0; c < C_; ++c) {
    float v = xb[(size_t)c * N_];
    s = fma((double)v, (double)v, s);
  }
  sq[idx] = (float)s;
}

// ---------------- symmetric MFMA Gram: rt<=mt tile pairs, global_load_lds staging --------
// grid 16*36: b = bid/36, pid -> (rt,mt). LDS: Ah@0 Al@8192 Bh@16384 Bl@24576, rows
// packed 64B with XOR-chunk swizzle pos = chunk ^ ((row>>1)&3) (2-way reads = free).
// D[64][130] overlays staging; row-scan (slot mt) + col-scan (slot rt, carried across
// the two 64-row phases). Diagonal: B aliases A (half staging), dup writes benign.
__global__ __launch_bounds__(256, 4) void k_gram(const ushort* __restrict__ xhT,
                                                 const ushort* __restrict__ xlT,
                                                 const float* __restrict__ sq,
                                                 float* __restrict__ cd,
                                                 int* __restrict__ ci) {
  const int bid = blockIdx.x;
  const int b = bid / 36;
  int rem = bid % 36, rt = 0;
  while (rem >= 8 - rt) { rem -= 8 - rt; ++rt; }
  const int mt = rt + rem;
  const int n0 = rt * 128, m0 = mt * 128;
  const bool diag = (rt == mt);

  __shared__ alignas(16) char sm[33280];
  const int t = threadIdx.x;
  const int lane = t & 63, wid = t >> 6, quad = lane >> 4, lrow = lane & 15;
  const int wr = wid >> 1, wc = wid & 1;
  const int lrow4 = lane >> 2, lpos = lane & 3;

  f32x4 acc[4][4];
#pragma unroll
  for (int mi = 0; mi < 4; ++mi)
#pragma unroll
    for (int ni = 0; ni < 4; ++ni) acc[mi][ni] = (f32x4){0.f, 0.f, 0.f, 0.f};

  const char* srcs[4] = {(const char*)(xhT + (size_t)(b * N_ + n0) * C_),
                         (const char*)(xlT + (size_t)(b * N_ + n0) * C_),
                         (const char*)(xhT + (size_t)(b * N_ + m0) * C_),
                         (const char*)(xlT + (size_t)(b * N_ + m0) * C_)};
  const int nChunk = diag ? 4 : 8;           // 1KB chunks per wave
  const int bh_off = diag ? 0 : 16384;       // B reads alias A on diagonal
  const int bl_off = diag ? 8192 : 24576;

  for (int ktB = 0; ktB < 768; ktB += 64) {
    __syncthreads();
    for (int i = 0; i < nChunk; ++i) {
      const int c = wid * nChunk + i;
      const int arr = c >> 3, sub = c & 7;
      const int row = sub * 16 + lrow4;
      const int g = lpos ^ ((row >> 1) & 3);
      gld_lds16(srcs[arr] + (size_t)row * 768 + ktB + g * 16,
                sm + arr * 8192 + sub * 1024 + lane * 16);
    }
    __syncthreads();
    f16x8 ah[4], al[4];
#pragma unroll
    for (int mi = 0; mi < 4; ++mi) {
      const int row = wr * 64 + mi * 16 + lrow;
      const int off = row * 64 + (quad ^ ((row >> 1) & 3)) * 16;
      ah[mi] = *(const f16x8*)(sm + off);
      al[mi] = *(const f16x8*)(sm + 8192 + off);
    }
#pragma unroll
    for (int ni = 0; ni < 4; ++ni) {
      const int row = wc * 64 + ni * 16 + lrow;
      const int off = row * 64 + (quad ^ ((row >> 1) & 3)) * 16;
      f16x8 bh = *(const f16x8*)(sm + bh_off + off);
      f16x8 bl = *(const f16x8*)(sm + bl_off + off);
#pragma unroll
      for (int mi = 0; mi < 4; ++mi) {
        acc[mi][ni] = __builtin_amdgcn_mfma_f32_16x16x32_f16(ah[mi], bh, acc[mi][ni], 0, 0, 0);
        acc[mi][ni] = __builtin_amdgcn_mfma_f32_16x16x32_f16(al[mi], bh, acc[mi][ni], 0, 0, 0);
        acc[mi][ni] = __builtin_amdgcn_mfma_f32_16x16x32_f16(ah[mi], bl, acc[mi][ni], 0, 0, 0);
      }
    }
  }

  // epilogue
  const float* sqb = sq + b * N_;
  float sqm[4];
#pragma unroll
  for (int ni = 0; ni < 4; ++ni) sqm[ni] = sqb[m0 + wc * 64 + ni * 16 + lrow];
  float sqn_[4][4];
#pragma unroll
  for (int mi = 0; mi < 4; ++mi)
#pragma unroll
    for (int r = 0; r < 4; ++r) sqn_[mi][r] = sqb[n0 + wr * 64 + mi * 16 + quad * 4 + r];

  float* D = (float*)sm;  // 64 x stride-130
  float cdist[K_];
  int cidx[K_];
#pragma unroll
  for (int k = 0; k < K_; ++k) { cdist[k] = 3.402823466e38f; cidx[k] = 0; }

  for (int ph = 0; ph < 2; ++ph) {
    __syncthreads();
    if (wr == ph) {
#pragma unroll
      for (int mi = 0; mi < 4; ++mi)
#pragma unroll
        for (int ni = 0; ni < 4; ++ni)
#pragma unroll
          for (int r = 0; r < 4; ++r) {
            const int rl = mi * 16 + quad * 4 + r;    // 0..63
            const int cl = wc * 64 + ni * 16 + lrow;  // 0..127
            const int ng = n0 + ph * 64 + rl, mg = m0 + cl;
            float d = fmaf(-2.f, acc[mi][ni][r], sqn_[mi][r] + sqm[ni]);
            if (mg == ng) d = 3.402823466e38f;
            D[rl * 130 + cl] = d;
          }
    }
    __syncthreads();
    if (t < 64) {  // row-scan: node n0+ph*64+t over cols m0..m0+127, slot mt
      float dist[K_];
      int idx9[K_];
#pragma unroll
      for (int k = 0; k < K_; ++k) { dist[k] = 3.402823466e38f; idx9[k] = 0; }
#pragma unroll 4
      for (int j = 0; j < 128; ++j) {  // ascending j => stable ties
        float d = D[t * 130 + j];
        if (d < dist[K_ - 1]) {
          float cdv = d;
          int cmv = m0 + j;
#pragma unroll
          for (int k = 0; k < K_; ++k) {
            if (dist[k] > cdv) {
              float td = dist[k];
              int tm = idx9[k];
              dist[k] = cdv;
              idx9[k] = cmv;
              cdv = td;
              cmv = tm;
            }
          }
        }
      }
      const int node = b * N_ + n0 + ph * 64 + t;
#pragma unroll
      for (int k = 0; k < K_; ++k) {
        cd[(size_t)(mt * 9 + k) * (B_ * N_) + node] = dist[k];
        ci[(size_t)(mt * 9 + k) * (B_ * N_) + node] = idx9[k];
      }
    } else if (t < 192) {  // col-scan: node m0+(t-64) over rows, slot rt (carries over ph)
      const int tc = t - 64;
#pragma unroll 4
      for (int r = 0; r < 64; ++r) {  // ascending row index => stable ties
        float d = D[r * 130 + tc];
        if (d < cdist[K_ - 1]) {
          float cdv = d;
          int cmv = n0 + ph * 64 + r;
#pragma unroll
          for (int k = 0; k < K_; ++k) {
            if (cdist[k] > cdv) {
              float td = cdist[k];
              int tm = cidx[k];
              cdist[k] = cdv;
              cidx[k] = cmv;
              cdv = td;
              cmv = tm;
            }
          }
        }
      }
    }
  }
  if (t >= 64 && t < 192) {
    const int node = b * N_ + m0 + (t - 64);
#pragma unroll
    for (int k = 0; k < K_; ++k) {
      cd[(size_t)(rt * 9 + k) * (B_ * N_) + node] = cdist[k];
      ci[(size_t)(rt * 9 + k) * (B_ * N_) + node] = cidx[k];
    }
  }
}

// ---------------- stable 8-way merge of sorted 9-lists ----------------
__global__ void k_merge(const float* __restrict__ cd, const int* __restrict__ ci,
                        int* __restrict__ nbr) {
  const int node = blockIdx.x * blockDim.x + threadIdx.x;
  float rd[9];
  int ri[9];
#pragma unroll
  for (int k = 0; k < K_; ++k) {
    rd[k] = cd[(size_t)k * (B_ * N_) + node];
    ri[k] = ci[(size_t)k * (B_ * N_) + node];
  }
#pragma unroll
  for (int l = 1; l < 8; ++l) {
#pragma unroll
    for (int e = 0; e < K_; ++e) {
      float d = cd[(size_t)(l * 9 + e) * (B_ * N_) + node];
      int ix = ci[(size_t)(l * 9 + e) * (B_ * N_) + node];
      bool in_ = (d < rd[8]) || (d == rd[8] && ix < ri[8]);
      if (in_) {
        rd[8] = d;
        ri[8] = ix;
#pragma unroll
        for (int k = 8; k >= 1; --k) {
          bool sw = (rd[k] < rd[k - 1]) || (rd[k] == rd[k - 1] && ri[k] < ri[k - 1]);
          float td = sw ? rd[k] : rd[k - 1];
          int ti = sw ? ri[k] : ri[k - 1];
          rd[k] = sw ? rd[k - 1] : rd[k];
          ri[k] = sw ? ri[k - 1] : ri[k];
          rd[k - 1] = td;
          ri[k - 1] = ti;
        }
      }
    }
  }
#pragma unroll
  for (int k = 0; k < K_; ++k) nbr[(size_t)node * K_ + k] = ri[k];
}

// ---------------- MFMA xw[b][co][n]: A=Wg(h/l), B=xT(h/l), global_load_lds staging -------
__global__ __launch_bounds__(256, 4) void k_xw(const ushort* __restrict__ xhT,
                                               const ushort* __restrict__ xlT,
                                               const ushort* __restrict__ WgH,
                                               const ushort* __restrict__ WgL,
                                               float* __restrict__ xw) {
  const int bid = blockIdx.x;  // ((b*8 + nt)*6 + ct)
  const int ct = bid % 6;
  const int nt = (bid / 6) & 7;
  const int b = bid / 48;
  const int co0 = ct * 64, n0 = nt * 128;
  __shared__ alignas(16) char sm[24576];  // Ah@0 Al@4096 Bh@8192 Bl@16384 (packed 64B rows)
  const int t = threadIdx.x;
  const int lane = t & 63, wid = t >> 6, quad = lane >> 4, lrow = lane & 15;
  const int wr = wid >> 1, wc = wid & 1;
  const int lrow4 = lane >> 2, lpos = lane & 3;

  f32x4 acc[2][4];
#pragma unroll
  for (int mi = 0; mi < 2; ++mi)
#pragma unroll
    for (int ni = 0; ni < 4; ++ni) acc[mi][ni] = (f32x4){0.f, 0.f, 0.f, 0.f};

  const char* asrc[2] = {(const char*)(WgH + (size_t)co0 * C_),
                         (const char*)(WgL + (size_t)co0 * C_)};
  const char* bsrc[2] = {(const char*)(xhT + (size_t)(b * N_ + n0) * C_),
                         (const char*)(xlT + (size_t)(b * N_ + n0) * C_)};

  for (int ktB = 0; ktB < 768; ktB += 64) {
    __syncthreads();
    for (int i = 0; i < 6; ++i) {  // 24 x 1KB chunks: A 8, B 16
      const int c = wid * 6 + i;
      const char* src;
      int base, row;
      if (c < 8) {
        const int arr = c >> 2, sub = c & 3;
        src = asrc[arr];
        base = arr * 4096 + sub * 1024;
        row = sub * 16 + lrow4;
      } else {
        const int cc = c - 8, arr = cc >> 3, sub = cc & 7;
        src = bsrc[arr];
        base = 8192 + arr * 8192 + sub * 1024;
        row = sub * 16 + lrow4;
      }
      const int g = lpos ^ ((row >> 1) & 3);
      gld_lds16(src + (size_t)row * 768 + ktB + g * 16, sm + base + lane * 16);
    }
    __syncthreads();
    f16x8 bh[4], bl[4];
#pragma unroll
    for (int ni = 0; ni < 4; ++ni) {
      const int row = wr * 64 + ni * 16 + lrow;
      const int off = row * 64 + (quad ^ ((row >> 1) & 3)) * 16;
      bh[ni] = *(const f16x8*)(sm + 8192 + off);
      bl[ni] = *(const f16x8*)(sm + 16384 + off);
    }
#pragma unroll
    for (int mi = 0; mi < 2; ++mi) {
      const int row = wc * 32 + mi * 16 + lrow;
      const int off = row * 64 + (quad ^ ((row >> 1) & 3)) * 16;
      f16x8 ah = *(const f16x8*)(sm + off);
      f16x8 al = *(const f16x8*)(sm + 4096 + off);
#pragma unroll
      for (int ni = 0; ni < 4; ++ni) {
        acc[mi][ni] = __builtin_amdgcn_mfma_f32_16x16x32_f16(ah, bh[ni], acc[mi][ni], 0, 0, 0);
        acc[mi][ni] = __builtin_amdgcn_mfma_f32_16x16x32_f16(al, bh[ni], acc[mi][ni], 0, 0, 0);
        acc[mi][ni] = __builtin_amdgcn_mfma_f32_16x16x32_f16(ah, bl[ni], acc[mi][ni], 0, 0, 0);
      }
    }
  }
#pragma unroll
  for (int mi = 0; mi < 2; ++mi)
#pragma unroll
    for (int ni = 0; ni < 4; ++ni)
#pragma unroll
      for (int r = 0; r < 4; ++r) {
        const int c_g = co0 + wc * 32 + mi * 16 + quad * 4 + r;
        const int n_g = n0 + wr * 64 + ni * 16 + lrow;
        xw[((size_t)b * C_ + c_g) * N_ + n_g] = acc[mi][ni][r];
      }
}

// ---------------- aggregate (deg==10 uniformly) + BN partial stats ----------------
__global__ __launch_bounds__(256) void k_agg(const float* __restrict__ xw,
                                             const int* __restrict__ nbr,
                                             const float* __restrict__ bg,
                                             float* __restrict__ out,
                                             float* __restrict__ stats) {
  const int c = blockIdx.x % C_;
  const int b = blockIdx.x / C_;
  __shared__ alignas(16) int nb_l[N_ * K_];
  __shared__ alignas(16) float row_l[N_];
  __shared__ float w1[4], w2[4];
  const int tid = threadIdx.x;
  const int4* gp = (const int4*)(nbr + (size_t)b * N_ * K_);
  int4* lp = (int4*)nb_l;
  for (int t = tid; t < N_ * K_ / 4; t += 256) lp[t] = gp[t];
  const float4* rp = (const float4*)(xw + ((size_t)b * C_ + c) * N_);
  float4* rl = (float4*)row_l;
  for (int t = tid; t < N_ / 4; t += 256) rl[t] = rp[t];
  __syncthreads();
  const float bgc = bg[c];
  float* outb = out + ((size_t)b * C_ + c) * N_;
  float s1 = 0.f, s2 = 0.f;
#pragma unroll
  for (int s = 0; s < 4; ++s) {
    const int n = tid + 256 * s;
    float a = row_l[n];
    const int* nn_ = &nb_l[n * K_];
#pragma unroll
    for (int k = 0; k < K_; ++k) a += row_l[nn_[k]];
    float y = fmaf(a, 0.099999994f, bgc);
    outb[n] = y;
    s1 += y;
    s2 = fmaf(y, y, s2);
  }
#pragma unroll
  for (int off = 32; off > 0; off >>= 1) {
    s1 += __shfl_down(s1, off, 64);
    s2 += __shfl_down(s2, off, 64);
  }
  const int lane = tid & 63, wid = tid >> 6;
  if (lane == 0) { w1[wid] = s1; w2[wid] = s2; }
  __syncthreads();
  if (tid == 0) {
    atomicAdd(&stats[c], w1[0] + w1[1] + w1[2] + w1[3]);
    atomicAdd(&stats[C_ + c], w2[0] + w2[1] + w2[2] + w2[3]);
  }
}

// ---------------- BN (batch stats) + tanh-GELU + residual ----------------
__global__ void k_bn(const float* __restrict__ x, const float* __restrict__ gamma,
                     const float* __restrict__ beta, const float* __restrict__ stats,
                     float* __restrict__ out) {
  const int f = blockIdx.x * blockDim.x + threadIdx.x;
  const int e = f * 4;
  const int c = (e >> 10) % C_;
  const float inv = 1.f / 16384.f;
  const float mu = stats[c] * inv;
  const float var = fmaf(-mu, mu, stats[C_ + c] * inv);
  const float sc = gamma[c] * rsqrtf(var + 1e-5f);
  const float sh = fmaf(-mu, sc, beta[c]);
  float4 y = ((const float4*)out)[f];
  float4 xv = ((const float4*)x)[f];
  auto gl = [](float z) {
    float z3 = z * z * z;
    float t = 0.7978845608028654f * fmaf(0.044715f, z3, z);
    float th = tanhf(t);
    return 0.5f * z * (1.f + th);
  };
  float4 o;
  o.x = gl(fmaf(y.x, sc, sh)) + xv.x;
  o.y = gl(fmaf(y.y, sc, sh)) + xv.y;
  o.z = gl(fmaf(y.z, sc, sh)) + xv.z;
  o.w = gl(fmaf(y.w, sc, sh)) + xv.w;
  ((float4*)out)[f] = o;
}

extern "C" void kernel_launch(void* const* d_in, const int* in_sizes, int n_in,
                              void* d_out, int out_size, void* d_ws, size_t ws_size,
                              hipStream_t stream) {
  const float* x = (const float*)d_in[0];
  const float* Wg = (const float*)d_in[1];
  const float* bg = (const float*)d_in[2];
  const float* gamma = (const float*)d_in[3];
  const float* beta = (const float*)d_in[4];
  float* out = (float*)d_out;

  char* ws = (char*)d_ws;
  ushort* xhT = (ushort*)ws;                    // @0          12,582,912
  ushort* xlT = (ushort*)(ws + 12582912);       // @12,582,912 12,582,912
  ushort* WgH = (ushort*)(ws + 25165824);       // @25,165,824    294,912
  ushort* WgL = (ushort*)(ws + 25460736);       // @25,460,736    294,912
  float* sq = (float*)(ws + 25755648);          // @25,755,648     65,536
  float* cd = (float*)(ws + 25821184);          // @25,821,184  4,718,592
  int* ci_ = (int*)(ws + 30539776);             // @30,539,776  4,718,592
  float* xw = (float*)(ws + 25821184);          // overlays cd/ci (dead after k_merge)
  int* nbr = (int*)(ws + 50987008);             // @50,987,008    589,824
  float* stats = (float*)(ws + 51576832);       // @51,576,832      3,072

  hipMemsetAsync(stats, 0, 2 * C_ * sizeof(float), stream);
  k_cvt<<<3072, 256, 0, stream>>>(x, xhT, xlT);
  k_cvtw<<<144, 256, 0, stream>>>(Wg, WgH, WgL);
  k_sq<<<64, 256, 0, stream>>>(x, sq);
  k_gram<<<576, 256, 0, stream>>>(xhT, xlT, sq, cd, ci_);
  k_merge<<<64, 256, 0, stream>>>(cd, ci_, nbr);
  k_xw<<<768, 256, 0, stream>>>(xhT, xlT, WgH, WgL, xw);
  k_agg<<<B_ * C_, 256, 0, stream>>>(xw, nbr, bg, out, stats);
  k_bn<<<6144, 256, 0, stream>>>(x, gamma, beta, stats, out);
}

// Round 5
// 299.174 us; speedup vs baseline: 2.6984x; 1.3600x over previous
//
#include <hip/hip_runtime.h>
#include <math.h>

#define B_ 16
#define C_ 384
#define N_ 1024
#define K_ 9

typedef _Float16 f16x8 __attribute__((ext_vector_type(8)));
typedef _Float16 f16x4 __attribute__((ext_vector_type(4)));
typedef float f32x4 __attribute__((ext_vector_type(4)));
typedef unsigned long long u64;

__device__ __forceinline__ void gld_lds16(const void* g, void* l) {
  __builtin_amdgcn_global_load_lds((const __attribute__((address_space(1))) void*)g,
                                   (__attribute__((address_space(3))) void*)l, 16, 0, 0);
}

// ---------------- transpose + fp16 split: x[b][c][n] -> xhT/xlT [b][n][c] ----------------
__global__ void k_cvt(const float* __restrict__ x, ushort* __restrict__ xhT,
                      ushort* __restrict__ xlT) {
  const int bid = blockIdx.x;  // ((b*16 + nt)*12 + ct)
  const int ct = bid % 12;
  const int nt = (bid / 12) & 15;
  const int b = bid / 192;
  const int c0 = ct * 32, n0 = nt * 64;
  __shared__ float ld[32 * 65];
  const int t = threadIdx.x;
  {
    const int c = t >> 3, n8 = (t & 7) * 8;
    const float* src = x + ((size_t)(b * C_ + c0 + c) * N_ + n0 + n8);
    float4 v0 = *(const float4*)src;
    float4 v1 = *(const float4*)(src + 4);
    float vv[8] = {v0.x, v0.y, v0.z, v0.w, v1.x, v1.y, v1.z, v1.w};
#pragma unroll
    for (int j = 0; j < 8; ++j) ld[c * 65 + n8 + j] = vv[j];
  }
  __syncthreads();
  {
    const int n = t >> 2, c8 = (t & 3) * 8;
    f16x8 hv, lv;
#pragma unroll
    for (int j = 0; j < 8; ++j) {
      float v = ld[(c8 + j) * 65 + n];
      _Float16 h = (_Float16)v;
      _Float16 l = (_Float16)(v - (float)h);
      hv[j] = h;
      lv[j] = l;
    }
    const size_t off = (size_t)(b * N_ + n0 + n) * C_ + c0 + c8;
    *(f16x8*)(xhT + off) = hv;
    *(f16x8*)(xlT + off) = lv;
  }
}

// ---------------- Wg -> WgH/WgL ----------------
__global__ void k_cvtw(const float* __restrict__ Wg, ushort* __restrict__ WgH,
                       ushort* __restrict__ WgL) {
  const int i = (blockIdx.x * 256 + threadIdx.x) * 4;  // 144 blocks
  float4 v = *(const float4*)(Wg + i);
  float vv[4] = {v.x, v.y, v.z, v.w};
  f16x4 hv, lv;
#pragma unroll
  for (int j = 0; j < 4; ++j) {
    _Float16 h = (_Float16)vv[j];
    hv[j] = h;
    lv[j] = (_Float16)(vv[j] - (float)h);
  }
  *(f16x4*)(WgH + i) = hv;
  *(f16x4*)(WgL + i) = lv;
}

// ---------------- sq[b][n] = sum_c x[b][c][n]^2 (fp64 accum) ----------------
__global__ void k_sq(const float* __restrict__ x, float* __restrict__ sq) {
  const int idx = blockIdx.x * blockDim.x + threadIdx.x;
  const int b = idx >> 10, n = idx & 1023;
  const float* xb = x + (size_t)b * C_ * N_ + n;
  double s = 0.0;
#pragma unroll 4
  for (int c = 0; c < C_; ++c) {
    float v = xb[(size_t)c * N_];
    s = fma((double)v, (double)v, s);
  }
  sq[idx] = (float)s;
}

// ---------------- MFMA Gram -> D[b_local][n][m] (pure GEMM, dbuf staging) ----------------
// grid nb*64. XCD swizzle (nb>=8): batch group = bid&7 -> L2-resident working set.
// LDS 2x32KB: per buf Ah@0 Al@8192 Bh@16384 Bl@24576, packed 64B rows, XOR-chunk swizzle.
// Prefetch distance 1: stage(it+1) issued before compute(it); the next barrier's drain
// waits on loads that are a full compute-phase old -> latency hidden.
__global__ __launch_bounds__(256, 2) void k_gram(const ushort* __restrict__ xhT,
                                                 const ushort* __restrict__ xlT,
                                                 const float* __restrict__ sq,
                                                 float* __restrict__ D, int base_b, int nb) {
  const int bid = blockIdx.x;
  int b_local, pid;
  if (nb >= 8) {
    const int x = bid & 7, j = bid >> 3, grp = nb >> 3;
    b_local = x * grp + (j >> 6);
    pid = j & 63;
  } else {
    b_local = bid >> 6;
    pid = bid & 63;
  }
  const int b = base_b + b_local;
  const int rt = pid >> 3, mt = pid & 7;
  const int n0 = rt * 128, m0 = mt * 128;

  __shared__ alignas(16) char sm[2][32768];
  const int t = threadIdx.x;
  const int lane = t & 63, wid = t >> 6, quad = lane >> 4, lrow = lane & 15;
  const int wr = wid >> 1, wc = wid & 1;
  const int lrow4 = lane >> 2, lpos = lane & 3;

  // wave -> array it stages: 0:Ah(n0,h) 1:Al(n0,l) 2:Bh(m0,h) 3:Bl(m0,l)
  const char* src = (const char*)((wid & 1) ? xlT : xhT) +
                    (size_t)(b * N_ + ((wid >> 1) ? m0 : n0)) * C_ * 2;

  f32x4 acc[4][4];
#pragma unroll
  for (int mi = 0; mi < 4; ++mi)
#pragma unroll
    for (int ni = 0; ni < 4; ++ni) acc[mi][ni] = (f32x4){0.f, 0.f, 0.f, 0.f};

  auto stage = [&](int it) {
    char* dst = sm[it & 1] + wid * 8192;
    const int ktB = it * 64;
#pragma unroll
    for (int i = 0; i < 8; ++i) {
      const int row = i * 16 + lrow4;
      const int swz = lpos ^ ((row >> 1) & 3);
      gld_lds16(src + (size_t)row * 768 + ktB + swz * 16, dst + i * 1024 + lane * 16);
    }
  };

  stage(0);
  for (int it = 0; it < 12; ++it) {
    __syncthreads();
    if (it < 11) stage(it + 1);
    const char* smb = sm[it & 1];
    f16x8 ah[4], al[4];
#pragma unroll
    for (int mi = 0; mi < 4; ++mi) {
      const int row = wr * 64 + mi * 16 + lrow;
      const int off = row * 64 + (quad ^ ((row >> 1) & 3)) * 16;
      ah[mi] = *(const f16x8*)(smb + off);
      al[mi] = *(const f16x8*)(smb + 8192 + off);
    }
#pragma unroll
    for (int ni = 0; ni < 4; ++ni) {
      const int row = wc * 64 + ni * 16 + lrow;
      const int off = row * 64 + (quad ^ ((row >> 1) & 3)) * 16;
      f16x8 bh = *(const f16x8*)(smb + 16384 + off);
      f16x8 bl = *(const f16x8*)(smb + 24576 + off);
#pragma unroll
      for (int mi = 0; mi < 4; ++mi) {
        acc[mi][ni] = __builtin_amdgcn_mfma_f32_16x16x32_f16(ah[mi], bh, acc[mi][ni], 0, 0, 0);
        acc[mi][ni] = __builtin_amdgcn_mfma_f32_16x16x32_f16(al[mi], bh, acc[mi][ni], 0, 0, 0);
        acc[mi][ni] = __builtin_amdgcn_mfma_f32_16x16x32_f16(ah[mi], bl, acc[mi][ni], 0, 0, 0);
      }
    }
  }

  // epilogue: d = (sq_n + sq_m) - 2g, diag -> FLT_MAX, direct store (L2 write-combines)
  const float* sqb = sq + b * N_;
  float sqm[4];
#pragma unroll
  for (int ni = 0; ni < 4; ++ni) sqm[ni] = sqb[m0 + wc * 64 + ni * 16 + lrow];
  float sqn_[4][4];
#pragma unroll
  for (int mi = 0; mi < 4; ++mi)
#pragma unroll
    for (int r = 0; r < 4; ++r) sqn_[mi][r] = sqb[n0 + wr * 64 + mi * 16 + quad * 4 + r];

  float* Db = D + (size_t)b_local * N_ * N_;
#pragma unroll
  for (int mi = 0; mi < 4; ++mi)
#pragma unroll
    for (int ni = 0; ni < 4; ++ni)
#pragma unroll
      for (int r = 0; r < 4; ++r) {
        const int ng = n0 + wr * 64 + mi * 16 + quad * 4 + r;
        const int mg = m0 + wc * 64 + ni * 16 + lrow;
        float d = fmaf(-2.f, acc[mi][ni][r], sqn_[mi][r] + sqm[ni]);
        if (ng == mg) d = 3.402823466e38f;
        Db[(size_t)ng * N_ + mg] = d;
      }
}

// ---------------- wave-per-node top-9 over D row (u64 lex keys, butterfly merge) ---------
__device__ __forceinline__ void ce9(u64& a, u64& b) {
  u64 lo = a < b ? a : b;
  u64 hi = a < b ? b : a;
  a = lo;
  b = hi;
}

__global__ __launch_bounds__(256) void k_scan(const float* __restrict__ D,
                                              int* __restrict__ nbr, int base_node) {
  const int lane = threadIdx.x & 63;
  const int nl = blockIdx.x * 4 + (threadIdx.x >> 6);
  const float* row = D + (size_t)nl * N_;
  u64 key[9];
#pragma unroll
  for (int k = 0; k < 9; ++k) key[k] = ~0ULL;
#pragma unroll
  for (int i = 0; i < 4; ++i) {
    float4 v = *(const float4*)(row + i * 256 + lane * 4);
    float vv[4] = {v.x, v.y, v.z, v.w};
#pragma unroll
    for (int j = 0; j < 4; ++j) {
      unsigned fb = __float_as_uint(vv[j]);
      unsigned mono = (fb >> 31) ? ~fb : (fb | 0x80000000u);  // monotone float->uint
      u64 kk = ((u64)mono << 32) | (unsigned)(i * 256 + lane * 4 + j);
      if (kk < key[8]) {  // lex (d, idx): matches stable top_k tie semantics
        key[8] = kk;
#pragma unroll
        for (int s = 8; s >= 1; --s) ce9(key[s - 1], key[s]);
      }
    }
  }
  // butterfly merge of sorted 9-lists: m[i]=min(a[i],b[8-i]) is bitonic; 13-CE cleanup
#pragma unroll
  for (int lvl = 1; lvl < 64; lvl <<= 1) {
    u64 pk[9];
#pragma unroll
    for (int k = 0; k < 9; ++k) pk[k] = __shfl_xor(key[k], lvl, 64);
    u64 m[9];
#pragma unroll
    for (int k = 0; k < 9; ++k) m[k] = key[k] < pk[8 - k] ? key[k] : pk[8 - k];
    ce9(m[0], m[8]);
    ce9(m[1], m[5]); ce9(m[2], m[6]); ce9(m[3], m[7]); ce9(m[4], m[8]);
    ce9(m[1], m[3]); ce9(m[2], m[4]); ce9(m[5], m[7]); ce9(m[6], m[8]);
    ce9(m[1], m[2]); ce9(m[3], m[4]); ce9(m[5], m[6]); ce9(m[7], m[8]);
#pragma unroll
    for (int k = 0; k < 9; ++k) key[k] = m[k];
  }
  if (lane == 0) {
    int* np = nbr + (size_t)(base_node + nl) * K_;
#pragma unroll
    for (int k = 0; k < 9; ++k) np[k] = (int)(unsigned)(key[k] & 0xFFFFFFFFu);
  }
}

// ---------------- MFMA xw[b][co][n]: A=Wg(h/l), B=xT(h/l), dbuf staging ----------------
__global__ __launch_bounds__(256, 3) void k_xw(const ushort* __restrict__ xhT,
                                               const ushort* __restrict__ xlT,
                                               const ushort* __restrict__ WgH,
                                               const ushort* __restrict__ WgL,
                                               float* __restrict__ xw) {
  const int bid = blockIdx.x;  // ((b*8 + nt)*6 + ct)
  const int ct = bid % 6;
  const int nt = (bid / 6) & 7;
  const int b = bid / 48;
  const int co0 = ct * 64, n0 = nt * 128;
  __shared__ alignas(16) char sm[2][24576];  // per buf: Ah@0 Al@4096 Bh@8192 Bl@16384
  const int t = threadIdx.x;
  const int lane = t & 63, wid = t >> 6, quad = lane >> 4, lrow = lane & 15;
  const int wr = wid >> 1, wc = wid & 1;
  const int lrow4 = lane >> 2, lpos = lane & 3;

  f32x4 acc[2][4];
#pragma unroll
  for (int mi = 0; mi < 2; ++mi)
#pragma unroll
    for (int ni = 0; ni < 4; ++ni) acc[mi][ni] = (f32x4){0.f, 0.f, 0.f, 0.f};

  const char* asrc[2] = {(const char*)(WgH + (size_t)co0 * C_),
                         (const char*)(WgL + (size_t)co0 * C_)};
  const char* bsrc[2] = {(const char*)(xhT + (size_t)(b * N_ + n0) * C_),
                         (const char*)(xlT + (size_t)(b * N_ + n0) * C_)};

  auto stage = [&](int it) {
    char* dst = sm[it & 1];
    const int ktB = it * 64;
#pragma unroll
    for (int i = 0; i < 6; ++i) {
      const int c = wid * 6 + i;
      const char* src;
      int base, row;
      if (c < 8) {
        const int arr = c >> 2, sub = c & 3;
        src = asrc[arr];
        base = arr * 4096 + sub * 1024;
        row = sub * 16 + lrow4;
      } else {
        const int cc = c - 8, arr = cc >> 3, sub = cc & 7;
        src = bsrc[arr];
        base = 8192 + arr * 8192 + sub * 1024;
        row = sub * 16 + lrow4;
      }
      const int swz = lpos ^ ((row >> 1) & 3);
      gld_lds16(src + (size_t)row * 768 + ktB + swz * 16, dst + base + lane * 16);
    }
  };

  stage(0);
  for (int it = 0; it < 12; ++it) {
    __syncthreads();
    if (it < 11) stage(it + 1);
    const char* smb = sm[it & 1];
    f16x8 bh[4], bl[4];
#pragma unroll
    for (int ni = 0; ni < 4; ++ni) {
      const int row = wr * 64 + ni * 16 + lrow;
      const int off = row * 64 + (quad ^ ((row >> 1) & 3)) * 16;
      bh[ni] = *(const f16x8*)(smb + 8192 + off);
      bl[ni] = *(const f16x8*)(smb + 16384 + off);
    }
#pragma unroll
    for (int mi = 0; mi < 2; ++mi) {
      const int row = wc * 32 + mi * 16 + lrow;
      const int off = row * 64 + (quad ^ ((row >> 1) & 3)) * 16;
      f16x8 ah = *(const f16x8*)(smb + off);
      f16x8 al = *(const f16x8*)(smb + 4096 + off);
#pragma unroll
      for (int ni = 0; ni < 4; ++ni) {
        acc[mi][ni] = __builtin_amdgcn_mfma_f32_16x16x32_f16(ah, bh[ni], acc[mi][ni], 0, 0, 0);
        acc[mi][ni] = __builtin_amdgcn_mfma_f32_16x16x32_f16(al, bh[ni], acc[mi][ni], 0, 0, 0);
        acc[mi][ni] = __builtin_amdgcn_mfma_f32_16x16x32_f16(ah, bl[ni], acc[mi][ni], 0, 0, 0);
      }
    }
  }
#pragma unroll
  for (int mi = 0; mi < 2; ++mi)
#pragma unroll
    for (int ni = 0; ni < 4; ++ni)
#pragma unroll
      for (int r = 0; r < 4; ++r) {
        const int c_g = co0 + wc * 32 + mi * 16 + quad * 4 + r;
        const int n_g = n0 + wr * 64 + ni * 16 + lrow;
        xw[((size_t)b * C_ + c_g) * N_ + n_g] = acc[mi][ni][r];
      }
}

// ---------------- aggregate (deg==10 uniformly) + BN partial stats ----------------
__global__ __launch_bounds__(256) void k_agg(const float* __restrict__ xw,
                                             const int* __restrict__ nbr,
                                             const float* __restrict__ bg,
                                             float* __restrict__ out,
                                             float* __restrict__ stats) {
  const int c = blockIdx.x % C_;
  const int b = blockIdx.x / C_;
  __shared__ alignas(16) int nb_l[N_ * K_];
  __shared__ alignas(16) float row_l[N_];
  __shared__ float w1[4], w2[4];
  const int tid = threadIdx.x;
  const int4* gp = (const int4*)(nbr + (size_t)b * N_ * K_);
  int4* lp = (int4*)nb_l;
  for (int t = tid; t < N_ * K_ / 4; t += 256) lp[t] = gp[t];
  const float4* rp = (const float4*)(xw + ((size_t)b * C_ + c) * N_);
  float4* rl = (float4*)row_l;
  for (int t = tid; t < N_ / 4; t += 256) rl[t] = rp[t];
  __syncthreads();
  const float bgc = bg[c];
  float* outb = out + ((size_t)b * C_ + c) * N_;
  float s1 = 0.f, s2 = 0.f;
#pragma unroll
  for (int s = 0; s < 4; ++s) {
    const int n = tid + 256 * s;
    float a = row_l[n];
    const int* nn_ = &nb_l[n * K_];
#pragma unroll
    for (int k = 0; k < K_; ++k) a += row_l[nn_[k]];
    float y = fmaf(a, 0.099999994f, bgc);
    outb[n] = y;
    s1 += y;
    s2 = fmaf(y, y, s2);
  }
#pragma unroll
  for (int off = 32; off > 0; off >>= 1) {
    s1 += __shfl_down(s1, off, 64);
    s2 += __shfl_down(s2, off, 64);
  }
  const int lane = tid & 63, wid = tid >> 6;
  if (lane == 0) { w1[wid] = s1; w2[wid] = s2; }
  __syncthreads();
  if (tid == 0) {
    atomicAdd(&stats[c], w1[0] + w1[1] + w1[2] + w1[3]);
    atomicAdd(&stats[C_ + c], w2[0] + w2[1] + w2[2] + w2[3]);
  }
}

// ---------------- BN (batch stats) + tanh-GELU + residual ----------------
__global__ void k_bn(const float* __restrict__ x, const float* __restrict__ gamma,
                     const float* __restrict__ beta, const float* __restrict__ stats,
                     float* __restrict__ out) {
  const int f = blockIdx.x * blockDim.x + threadIdx.x;
  const int e = f * 4;
  const int c = (e >> 10) % C_;
  const float inv = 1.f / 16384.f;
  const float mu = stats[c] * inv;
  const float var = fmaf(-mu, mu, stats[C_ + c] * inv);
  const float sc = gamma[c] * rsqrtf(var + 1e-5f);
  const float sh = fmaf(-mu, sc, beta[c]);
  float4 y = ((const float4*)out)[f];
  float4 xv = ((const float4*)x)[f];
  auto gl = [](float z) {
    float z3 = z * z * z;
    float t = 0.7978845608028654f * fmaf(0.044715f, z3, z);
    float th = tanhf(t);
    return 0.5f * z * (1.f + th);
  };
  float4 o;
  o.x = gl(fmaf(y.x, sc, sh)) + xv.x;
  o.y = gl(fmaf(y.y, sc, sh)) + xv.y;
  o.z = gl(fmaf(y.z, sc, sh)) + xv.z;
  o.w = gl(fmaf(y.w, sc, sh)) + xv.w;
  ((float4*)out)[f] = o;
}

extern "C" void kernel_launch(void* const* d_in, const int* in_sizes, int n_in,
                              void* d_out, int out_size, void* d_ws, size_t ws_size,
                              hipStream_t stream) {
  const float* x = (const float*)d_in[0];
  const float* Wg = (const float*)d_in[1];
  const float* bg = (const float*)d_in[2];
  const float* gamma = (const float*)d_in[3];
  const float* beta = (const float*)d_in[4];
  float* out = (float*)d_out;

  // rounds adapt to ws_size; nb=4 layout totals 51,579,904 B (== proven R4 footprint)
  int nb;
  if (ws_size >= 94000000) nb = 16;
  else if (ws_size >= 60500000) nb = 8;
  else nb = 4;

  char* ws = (char*)d_ws;
  ushort* xhT = (ushort*)ws;                  // @0          12,582,912
  ushort* xlT = (ushort*)(ws + 12582912);     //             12,582,912
  ushort* WgH = (ushort*)(ws + 25165824);     //                294,912
  ushort* WgL = (ushort*)(ws + 25460736);     //                294,912
  float* sq = (float*)(ws + 25755648);        //                 65,536
  float* Dbuf = (float*)(ws + 25821184);      // nb*4,194,304
  float* xw = (float*)(ws + 25821184);        // overlays Dbuf (Dbuf dead after scans)
  size_t dreg = (size_t)nb * 4194304;
  if (dreg < 25165824) dreg = 25165824;       // xw needs 25.17 MB
  int* nbr = (int*)(ws + 25821184 + dreg);    //                589,824
  float* stats = (float*)(ws + 25821184 + dreg + 589824);  //     3,072

  hipMemsetAsync(stats, 0, 2 * C_ * sizeof(float), stream);
  k_cvt<<<3072, 256, 0, stream>>>(x, xhT, xlT);
  k_cvtw<<<144, 256, 0, stream>>>(Wg, WgH, WgL);
  k_sq<<<64, 256, 0, stream>>>(x, sq);
  for (int r = 0; r < B_ / nb; ++r) {
    k_gram<<<nb * 64, 256, 0, stream>>>(xhT, xlT, sq, Dbuf, r * nb, nb);
    k_scan<<<nb * 256, 256, 0, stream>>>(Dbuf, nbr, r * nb * N_);
  }
  k_xw<<<768, 256, 0, stream>>>(xhT, xlT, WgH, WgL, xw);
  k_agg<<<B_ * C_, 256, 0, stream>>>(xw, nbr, bg, out, stats);
  k_bn<<<6144, 256, 0, stream>>>(x, gamma, beta, stats, out);
}